// Round 12
// baseline (472.247 us; speedup 1.0000x reference)
//
#include <hip/hip_runtime.h>

// SRGNN — Round 20: revert phase 3 to measured-best r16 form + cnt-fold.
//  r19 post-mortem: static t-split + setprio REGRESSED k_mono 296.8->317us
//  (VGPR 52->60, MfmaUtil 13.8->12.7): the split issues back-to-back dependent
//  MFMAs on the same accumulator (rr=mfma(a,..,rr); rr=mfma(f,..,rr)) — a
//  serial chain per iteration — and 5 live weight frags raised pressure.
//  r16's merged loop (compiler interleaves independent gates) was better.
//  Changes vs r19:
//   1. phase 3 = r16's exact merged U+V loop (unroll 2, dynamic if(t<4),
//      no setprio) — known 296.8us.
//   2. cnt folded into the s_e atomic (16 mults/wave) instead of multiplied
//      per-element in the output loop (was 128 thr x 32 iters = 4096 mults).
//  If k_mono ~295 and total ~470: practical floor of this structure — pipes
//  <40%, occupancy at reg-granule cap, zero spill, ideal traffic; remainder
//  is exposed latency + fixed harness overhead.
//  Tripwires: WRITE >> 8.2MB => spill; absmax shift => cnt-fold bug.
// ws: [0] flag ; [4K] bf16 conv (~419KB) ; [430K] bw_in/bw_og f32 ;
//     [448K] u_t bf16 384x256 (192KB) ; [1MiB] adj u8 (8MB).

#define NG    8192
#define HDIM  128
#define NEDGE 524288
#define NCONV 214272

typedef __bf16 bf16;
typedef __bf16 bf16x8 __attribute__((ext_vector_type(8)));
typedef float  f32x4  __attribute__((ext_vector_type(4)));
typedef unsigned int u32;
typedef unsigned char u8;

__device__ __forceinline__ f32x4 mfma16(bf16x8 a, bf16x8 b, f32x4 c) {
    // D = A(16x32)*B(32x16)+C ; A[m=lane&15][k=quad*8+j], B[k=quad*8+j][n=lane&15],
    // D[row=quad*4+r][col=lane&15]
    return __builtin_amdgcn_mfma_f32_16x16x32_bf16(a, b, c, 0, 0, 0);
}

__device__ __forceinline__ float sigmoidf_(float x) { return 1.f / (1.f + __expf(-x)); }
__device__ __forceinline__ float tanhf_(float x) { return 1.f - 2.f / (__expf(2.f * x) + 1.f); }

// ---- k_prep: 105 convert blocks (zeroing via hipMemsetAsync) ---------------
__global__ __launch_bounds__(256) void k_prep(
        const u32* __restrict__ featw,
        bf16* __restrict__ conv, u32* __restrict__ flagout,
        const void* t0, const void* t1, const void* t2,  const void* t3,
        const void* t4, const void* t5, const void* t6,  const void* t7,
        const void* t8, const void* t9, const void* t10, const void* t11) {
    const int b = blockIdx.x, tid = threadIdx.x;
    __shared__ int s_isf32;
    if (tid == 0) s_isf32 = 0;
    __syncthreads();
    {
        u32 hit = 0;
#pragma unroll
        for (int k = 0; k < 16; ++k) {
            u32 x = featw[tid * 16 + k];
            hit |= (((x >> 7) & 0xFFu) == 0xFFu) ? 1u : 0u;
        }
        if (hit) s_isf32 = 1;             // benign race
    }
    __syncthreads();
    const bool isf32 = s_isf32 != 0;
    if (b == 0 && tid == 0) *flagout = isf32 ? 1u : 0u;

    int e0 = b * 2048 + tid * 8;
    if (e0 >= NCONV) return;
    const int cnts[12] = {16384, 128, 16384, 128, 98304, 384, 49152, 384,
                          16384, 16384, 128, 128};
    int t = 0, base = 0;
    while (e0 >= base + cnts[t]) { base += cnts[t]; ++t; }
    int off = e0 - base;
    const void* sp;
    switch (t) {
        case 0: sp = t0; break; case 1: sp = t1; break;
        case 2: sp = t2; break; case 3: sp = t3; break;
        case 4: sp = t4; break; case 5: sp = t5; break;
        case 6: sp = t6; break; case 7: sp = t7; break;
        case 8: sp = t8; break; case 9: sp = t9; break;
        case 10: sp = t10; break; default: sp = t11; break;
    }
    if (isf32) {
        const float4* s = (const float4*)sp + (off >> 2);
        float4 a = s[0], bb = s[1];
        bf16x8 v;
        v[0] = (bf16)a.x;  v[1] = (bf16)a.y;  v[2] = (bf16)a.z;  v[3] = (bf16)a.w;
        v[4] = (bf16)bb.x; v[5] = (bf16)bb.y; v[6] = (bf16)bb.z; v[7] = (bf16)bb.w;
        *(bf16x8*)(conv + e0) = v;
    } else {
        *(uint4*)(conv + e0) = ((const uint4*)sp)[off >> 3];
    }
}

// ---- k_fuse: 96 blocks (jt = b>>2, ksel = b&3) -----------------------------
__global__ __launch_bounds__(256) void k_fuse(
        const bf16* __restrict__ W_in, const bf16* __restrict__ b_in,
        const bf16* __restrict__ W_og, const bf16* __restrict__ b_og,
        const bf16* __restrict__ W_ih, const bf16* __restrict__ b_ih,
        bf16* __restrict__ u_t, float* __restrict__ bw_in,
        float* __restrict__ bw_og) {
    const int jt = blockIdx.x >> 2;            // 0..23
    const int ksel = blockIdx.x & 3;
    const int tid = threadIdx.x;
    const int wave = tid >> 6, lane = tid & 63, q = lane >> 4, c = lane & 15;
    {
        int kt = wave * 4 + ksel;              // 0..15 (col tile of 256)
        bool og = kt >= 8;
        const bf16* Wsrc = og ? W_og : W_in;   // [128][128] row-major
        int kcol = (kt & 7) * 16 + c;          // 0..127
        int mo = og ? 128 : 0;
        f32x4 acc = {0, 0, 0, 0};
#pragma unroll 1
        for (int t = 0; t < 4; ++t) {
            bf16x8 a = *(const bf16x8*)(W_ih + (jt * 16 + c) * 256 + mo + 32 * t + 8 * q);
            bf16x8 b;
#pragma unroll
            for (int jj = 0; jj < 8; ++jj)
                b[jj] = Wsrc[(32 * t + 8 * q + jj) * 128 + kcol];
            acc = mfma16(a, b, acc);
        }
#pragma unroll
        for (int r = 0; r < 4; ++r)
            u_t[(size_t)(jt * 16 + q * 4 + r) * 256 + kt * 16 + c] = (bf16)acc[r];
    }
    if (ksel == 0) {   // bias: jj = tid>>4 (16 j's), mm = tid&15, shfl reduce
        int jj = tid >> 4, mm = tid & 15;
        int j = jt * 16 + jj;
        float si = 0.f, so = 0.f;
#pragma unroll
        for (int i = 0; i < 8; ++i) {
            int m = mm * 8 + i;
            si += (float)b_in[m] * (float)W_ih[j * 256 + m];
            so += (float)b_og[m] * (float)W_ih[j * 256 + 128 + m];
        }
        for (int m = 1; m < 16; m <<= 1) {
            si += __shfl_xor(si, m);
            so += __shfl_xor(so, m);
        }
        if (mm == 0) { bw_in[j] = si; bw_og[j] = so; }
    }
}

__global__ __launch_bounds__(256) void k_adj(const int* __restrict__ src,
                                             const int* __restrict__ dst,
                                             u32* __restrict__ adj) {
    int e = blockIdx.x * 256 + threadIdx.x;
    int s = src[e], d = dst[e];
    int g = s >> 5;                          // edges are intra-graph
    u32 bidx = ((u32)g << 10) | ((u32)(d & 31) << 5) | (u32)(s & 31);
    atomicAdd(&adj[bidx >> 2], 1u << (8 * (bidx & 3)));
}

__global__ __launch_bounds__(512, 4) void k_mono(
        const void* __restrict__ featv, const void* __restrict__ cntv,
        const bf16* __restrict__ u_t,  const bf16* __restrict__ b_ih,
        const bf16* __restrict__ W_hh, const bf16* __restrict__ b_hh,
        const bf16* __restrict__ W_u,  const bf16* __restrict__ W_v,
        const bf16* __restrict__ b_v,  const bf16* __restrict__ w_e,
        const float* __restrict__ bw_in, const float* __restrict__ bw_og,
        const int* __restrict__ last_nodes, const u8* __restrict__ adj8,
        const u32* __restrict__ flag, float* __restrict__ out) {
    const int g2   = blockIdx.x;            // graph pair: graphs 2*g2, 2*g2+1
    const int tid  = threadIdx.x;
    const int wave = tid >> 6, lane = tid & 63, q = lane >> 4, c = lane & 15;
    const bool isf32 = (*flag) != 0u;
    const int col  = wave * 16 + c;         // this wave's output column (0..127)

    const int SF = 136;   // bf16 stride, feat tile (pad 8)
    const int SC = 264;   // bf16 stride, P tile (pad 8)
    const int SA = 40;    // bf16 stride, adjacency (pad 8)
    const int SH = 136;   // bf16 stride, hnp/hn tile (16B-aligned rows)
    __shared__ __align__(16) bf16 s_feat[64 * 136];   // 17408 B (feat, stays feat)
    __shared__ __align__(16) bf16 s_fc  [64 * 264];   // 33792 B (P; adjw aliased)
    __shared__ __align__(16) bf16 s_adjb[64 * 40];    // 5120 B  adj[v][u]
    __shared__ __align__(16) bf16 s_adjT[64 * 40];    // 5120 B  adj[u][v]
    __shared__ __align__(16) bf16 s_hnp [64 * 136];   // 17408 B hnp, then hn
    __shared__ float s_invin[64], s_invout[64];
    __shared__ float s_din[64], s_dout[64];
    __shared__ float s_e[64], s_cnt[64];
    u32* s_adjw = (u32*)s_fc;   // alias: read pre-B1 only; s_fc written post-B1

    // ---------- phase 0: stage feat + adj word + adjb/adjT + cnt + e=0 ------
    if (isf32) {
        const float4* fp = (const float4*)((const float*)featv + (size_t)g2 * 8192);
        for (int ch = tid; ch < 2048; ch += 512) {
            float4 v = fp[ch];
            int row = ch >> 5, off = (ch & 31) * 4;
            bf16* dp = s_feat + row * SF + off;
            dp[0] = (bf16)v.x; dp[1] = (bf16)v.y; dp[2] = (bf16)v.z; dp[3] = (bf16)v.w;
        }
    } else {
        const uint4* fp = (const uint4*)((const bf16*)featv + (size_t)g2 * 8192);
        for (int ch = tid; ch < 1024; ch += 512) {
            int row = ch >> 4, off = (ch & 15) * 8;
            *(uint4*)(s_feat + row * SF + off) = fp[ch];
        }
    }
    {
        u32 w = ((const u32*)(adj8 + (size_t)g2 * 2048))[tid];
        s_adjw[tid] = w;
        int vrow = tid >> 3;            // global row 0..63
        int grp  = tid >> 8;            // graph within pair
        int vloc = vrow & 31;
        int u0 = (tid & 7) * 4;
#pragma unroll
        for (int j = 0; j < 4; ++j) {
            float cv = (float)((w >> (8 * j)) & 0xFFu);
            s_adjb[vrow * SA + u0 + j] = (bf16)cv;
            s_adjT[(grp * 32 + u0 + j) * SA + vloc] = (bf16)cv;
        }
    }
    if (tid < 64) {
        s_e[tid] = 0.f;
        s_cnt[tid] = isf32 ? ((const float*)cntv)[(size_t)g2 * 64 + tid]
                           : (float)((const bf16*)cntv)[(size_t)g2 * 64 + tid];
    }
    __syncthreads();   // B0

    // ---------- phase 1: degrees (from s_adjw alias) + hnp GEMM -------------
    if (tid < 64) {                                  // deg_in[row] = row-sum
        u32 s = 0;
#pragma unroll
        for (int i = 0; i < 8; ++i) {
            u32 w = s_adjw[tid * 8 + i];
            s += (w & 0xFF) + ((w >> 8) & 0xFF) + ((w >> 16) & 0xFF) + (w >> 24);
        }
        s_invin[tid] = 1.f / fmaxf((float)s, 1.f);
        s_din[tid] = (s > 0) ? 1.f : 0.f;
    } else if (tid < 128) {                          // deg_out = col-sum
        int uu = tid - 64; int grp = uu >> 5; int ul = uu & 31; u32 s = 0;
#pragma unroll 8
        for (int v = 0; v < 32; ++v)
            s += (s_adjw[grp * 256 + v * 8 + (ul >> 2)] >> (8 * (ul & 3))) & 0xFF;
        s_invout[uu] = 1.f / fmaxf((float)s, 1.f);
        s_dout[uu] = (s > 0) ? 1.f : 0.f;
    }
    // hnp = feat @ W_hh_n^T + b -> s_hnp (wave-private cols)
    {
        f32x4 hp[4] = {{0,0,0,0},{0,0,0,0},{0,0,0,0},{0,0,0,0}};
        const bf16* Vp = W_hh + (256 + col) * HDIM;
#pragma unroll 1
        for (int t = 0; t < 4; ++t) {
            bf16x8 b = *(const bf16x8*)(Vp + 32 * t + 8 * q);
#pragma unroll
            for (int fr = 0; fr < 4; ++fr) {
                bf16x8 a = *(const bf16x8*)(s_feat + (fr * 16 + c) * SF + 32 * t + 8 * q);
                hp[fr] = mfma16(a, b, hp[fr]);
            }
        }
        float bh = (float)b_hh[256 + col];
#pragma unroll
        for (int fr = 0; fr < 4; ++fr)
#pragma unroll
            for (int r = 0; r < 4; ++r)
                s_hnp[(fr * 16 + q * 4 + r) * SH + col] = (bf16)(hp[fr][r] + bh);
    }
    __syncthreads();   // B1 (degrees + hnp ready; s_adjw alias now dead)

    // ---------- phase 2: P = [invin*(adj@feat) | invout*(adjT@feat)] --------
#pragma unroll
    for (int kk = 0; kk < 2; ++kk) {
        int ct = wave * 2 + kk;                // 0..15
        int colb = (ct & 7) * 16;
        const bf16* Ab = (ct < 8) ? s_adjb : s_adjT;
        const float* inv = (ct < 8) ? s_invin : s_invout;
        bf16x8 bA, bB;
        const bf16* Bp0 = s_feat + (q * 8) * SF + colb + c;
        const bf16* Bp1 = s_feat + (32 + q * 8) * SF + colb + c;
#pragma unroll
        for (int jj = 0; jj < 8; ++jj) { bA[jj] = Bp0[jj * SF]; bB[jj] = Bp1[jj * SF]; }
        bf16x8 a0 = *(const bf16x8*)(Ab + c * SA + 8 * q);
        bf16x8 a1 = *(const bf16x8*)(Ab + (16 + c) * SA + 8 * q);
        bf16x8 a2 = *(const bf16x8*)(Ab + (32 + c) * SA + 8 * q);
        bf16x8 a3 = *(const bf16x8*)(Ab + (48 + c) * SA + 8 * q);
        f32x4 z = {0, 0, 0, 0};
        f32x4 p0 = mfma16(a0, bA, z);
        f32x4 p1 = mfma16(a1, bA, z);
        f32x4 p2 = mfma16(a2, bB, z);
        f32x4 p3 = mfma16(a3, bB, z);
#pragma unroll
        for (int r = 0; r < 4; ++r) {
            int r0 = q * 4 + r;
            s_fc[(r0)      * SC + ct * 16 + c] = (bf16)(p0[r] * inv[r0]);
            s_fc[(16 + r0) * SC + ct * 16 + c] = (bf16)(p1[r] * inv[16 + r0]);
            s_fc[(32 + r0) * SC + ct * 16 + c] = (bf16)(p2[r] * inv[32 + r0]);
            s_fc[(48 + r0) * SC + ct * 16 + c] = (bf16)(p3[r] * inv[48 + r0]);
        }
    }
    __syncthreads();   // B2

    // ---------- phase 3: GRU — r16's merged U+V loop (measured best) --------
    f32x4 rr[4] = {{0,0,0,0},{0,0,0,0},{0,0,0,0},{0,0,0,0}};
    f32x4 zz[4] = {{0,0,0,0},{0,0,0,0},{0,0,0,0},{0,0,0,0}};
    f32x4 in_[4] = {{0,0,0,0},{0,0,0,0},{0,0,0,0},{0,0,0,0}};
    {
        const bf16* Ur = u_t + (size_t)(col) * 256;
        const bf16* Uz = u_t + (size_t)(128 + col) * 256;
        const bf16* Un = u_t + (size_t)(256 + col) * 256;
        const bf16* Vr = W_hh + (col) * HDIM;
        const bf16* Vz = W_hh + (128 + col) * HDIM;
#pragma unroll 2
        for (int t = 0; t < 8; ++t) {
            bf16x8 br = *(const bf16x8*)(Ur + 32 * t + 8 * q);
            bf16x8 bz = *(const bf16x8*)(Uz + 32 * t + 8 * q);
            bf16x8 bn = *(const bf16x8*)(Un + 32 * t + 8 * q);
#pragma unroll
            for (int fr = 0; fr < 4; ++fr) {
                bf16x8 a = *(const bf16x8*)(s_fc + (fr * 16 + c) * SC + 32 * t + 8 * q);
                rr[fr] = mfma16(a, br, rr[fr]);
                zz[fr] = mfma16(a, bz, zz[fr]);
                in_[fr] = mfma16(a, bn, in_[fr]);
            }
            if (t < 4) {
                bf16x8 vr = *(const bf16x8*)(Vr + 32 * t + 8 * q);
                bf16x8 vz = *(const bf16x8*)(Vz + 32 * t + 8 * q);
#pragma unroll
                for (int fr = 0; fr < 4; ++fr) {
                    bf16x8 f = *(const bf16x8*)(s_feat + (fr * 16 + c) * SF + 32 * t + 8 * q);
                    rr[fr] = mfma16(f, vr, rr[fr]);
                    zz[fr] = mfma16(f, vz, zz[fr]);
                }
            }
        }
    }
    // epilogue: read hnp (own cols) -> hv; then overwrite s_hnp with hn
    f32x4 hv[4];
    {
        float brz  = (float)b_ih[col]       + (float)b_hh[col];
        float bzz  = (float)b_ih[128 + col] + (float)b_hh[128 + col];
        float bin_ = (float)b_ih[256 + col];
        float bwr_i = bw_in[col],       bwr_o = bw_og[col];
        float bwz_i = bw_in[128 + col], bwz_o = bw_og[128 + col];
        float bwn_i = bw_in[256 + col], bwn_o = bw_og[256 + col];
#pragma unroll
        for (int fr = 0; fr < 4; ++fr) {
#pragma unroll
            for (int r = 0; r < 4; ++r) {
                int row = fr * 16 + q * 4 + r;
                float di = s_din[row], dou = s_dout[row];
                float rg = sigmoidf_(rr[fr][r] + brz + di * bwr_i + dou * bwr_o);
                float z_ = sigmoidf_(zz[fr][r] + bzz + di * bwz_i + dou * bwz_o);
                float ng = tanhf_(in_[fr][r] + bin_ + di * bwn_i + dou * bwn_o
                                  + rg * (float)s_hnp[row * SH + col]);
                float fv = (float)s_feat[row * SF + col];
                hv[fr][r] = (1.f - z_) * ng + z_ * fv;
            }
        }
    }
    int llA = last_nodes[2 * g2] & 31;
    int llB = 32 + (last_nodes[2 * g2 + 1] & 31);
#pragma unroll
    for (int fr = 0; fr < 4; ++fr)
#pragma unroll
        for (int r = 0; r < 4; ++r)
            s_hnp[(fr * 16 + q * 4 + r) * SH + col] = (bf16)hv[fr][r];
    __syncthreads();   // B3 (hn visible everywhere)
    const bf16* s_hn = s_hnp;

    // ---------- phase 4+5: fv in regs, then e via MFMA + shfl + s_e atomics -
    float fvA, fvB;
    {
        const bf16* Wp = W_v + (size_t)col * HDIM;
        f32x4 accA = {0, 0, 0, 0}, accB = {0, 0, 0, 0};
#pragma unroll 2
        for (int t = 0; t < 4; ++t) {
            bf16x8 b  = *(const bf16x8*)(Wp + 32 * t + 8 * q);
            bf16x8 aA = *(const bf16x8*)(s_hn + llA * SH + 32 * t + 8 * q);
            bf16x8 aB = *(const bf16x8*)(s_hn + llB * SH + 32 * t + 8 * q);
            accA = mfma16(aA, b, accA);
            accB = mfma16(aB, b, accB);
        }
        // broadcast-A: every lane's acc[0] == fv[col] (A rows identical)
        fvA = accA[0] + (float)b_v[col];
        fvB = accB[0] + (float)b_v[col];
    }
    {
        const bf16* Wp = W_u + (size_t)col * HDIM;
        f32x4 ee[4] = {{0,0,0,0},{0,0,0,0},{0,0,0,0},{0,0,0,0}};
#pragma unroll 2
        for (int t = 0; t < 4; ++t) {
            bf16x8 b = *(const bf16x8*)(Wp + 32 * t + 8 * q);
#pragma unroll
            for (int fr = 0; fr < 4; ++fr) {
                bf16x8 a = *(const bf16x8*)(s_hn + (fr * 16 + c) * SH + 32 * t + 8 * q);
                ee[fr] = mfma16(a, b, ee[fr]);
            }
        }
        float we = (float)w_e[col];
#pragma unroll
        for (int fr = 0; fr < 4; ++fr) {
            float fv = (fr < 2) ? fvA : fvB;
#pragma unroll
            for (int r = 0; r < 4; ++r) {
                float v = sigmoidf_(ee[fr][r] + fv) * we;
                for (int m = 1; m < 16; m <<= 1) v += __shfl_xor(v, m);
                if (c == 0) {
                    int row = fr * 16 + q * 4 + r;
                    // cnt folded here: 16 mults/wave replaces 4096 in output
                    atomicAdd(&s_e[row], v * s_cnt[row]);
                }
            }
        }
    }
    __syncthreads();   // B5 (s_e final, already alpha = e*cnt)

    // ---------- output (f32): per graph [ct_g (128) | ct_l (128)] -----------
    {
        int part = tid >> 7;        // 0..3
        int co = tid & 127;
        if (part == 0) {
            float s = 0.f;
#pragma unroll 8
            for (int n = 0; n < 32; ++n)
                s += s_e[n] * (float)s_hn[n * SH + co];
            out[(size_t)(2 * g2) * 256 + co] = s;
        } else if (part == 1) {
            out[(size_t)(2 * g2) * 256 + 128 + co] = (float)s_hn[llA * SH + co];
        } else if (part == 2) {
            float s = 0.f;
#pragma unroll 8
            for (int n = 32; n < 64; ++n)
                s += s_e[n] * (float)s_hn[n * SH + co];
            out[(size_t)(2 * g2 + 1) * 256 + co] = s;
        } else {
            out[(size_t)(2 * g2 + 1) * 256 + 128 + co] = (float)s_hn[llB * SH + co];
        }
    }
}

extern "C" void kernel_launch(void* const* d_in, const int* in_sizes, int n_in,
                              void* d_out, int out_size, void* d_ws, size_t ws_size,
                              hipStream_t stream) {
    const int* src  = (const int*)d_in[14];
    const int* dst  = (const int*)d_in[15];
    const int* last = (const int*)d_in[17];
    float* out = (float*)d_out;

    u32*  flag  = (u32*)d_ws;
    bf16* conv  = (bf16*)((char*)d_ws + 4096);
    float* bwin = (float*)((char*)d_ws + 430 * 1024);
    float* bwog = (float*)((char*)d_ws + 434 * 1024);
    bf16* u_t   = (bf16*)((char*)d_ws + 448 * 1024);   // 384x256 bf16 = 192KB
    u32*  adjw  = (u32*)((char*)d_ws + (1u << 20));
    const u8* adj8 = (const u8*)adjw;

    // bf16 weight copies, contiguous in input order 2..13
    const int cnts[12] = {16384, 128, 16384, 128, 98304, 384, 49152, 384,
                          16384, 16384, 128, 128};
    bf16* cp[12];
    {
        bf16* p = conv;
        for (int i = 0; i < 12; ++i) { cp[i] = p; p += cnts[i]; }
    }

    hipMemsetAsync(adjw, 0, 8u << 20, stream);          // zero adj
    k_prep<<<(NCONV + 2047) / 2048, 256, 0, stream>>>(
        (const u32*)d_in[0], conv, flag,
        d_in[2], d_in[3], d_in[4], d_in[5], d_in[6], d_in[7],
        d_in[8], d_in[9], d_in[10], d_in[11], d_in[12], d_in[13]);
    k_fuse<<<96, 256, 0, stream>>>(cp[0], cp[1], cp[2], cp[3], cp[4], cp[5],
                                   u_t, bwin, bwog);
    k_adj<<<NEDGE / 256, 256, 0, stream>>>(src, dst, adjw);
    k_mono<<<NG / 2, 512, 0, stream>>>(d_in[0], d_in[1],
                                       u_t, cp[5], cp[6], cp[7],
                                       cp[8], cp[9], cp[10], cp[11],
                                       bwin, bwog,
                                       last, adj8, flag, out);
}